// Round 10
// baseline (32.313 us; speedup 1.0000x reference)
//
#include <hip/hip_runtime.h>
#include <math.h>

#define NB 64
#define NL 512
#define NC 768
#define NP 196
#define MAXM 32      // max distinct valid labels per batch (m ~ Poisson(1.31))
#define RT 14        // blocks per batch
#define RPB 14       // rows per block (RT*RPB == NP)
#define RPW 2        // rows per wave (7 waves * RPW == RPB)
#define NWV 7        // waves per block
#define NT 448       // threads per block
#define SCH 4        // tpe slots per LDS chunk

// ---------------------------------------------------------------------------
// Single fused kernel, ZERO fences. Cross-block data moves only through
// atomic writes (write-through to the coherence point) + s_waitcnt vmcnt(0)
// ordering + atomic-RMW reads. Grid (NB, RT), 448 threads (7 waves x 2 rows).
// Phases: redundant deterministic labels/compaction -> tpe in LDS -> stream
// 14 ipe rows (online row-LSE, gmat via atomicExch) -> per-block rowsum via
// atomicExch -> batch-last block (atomic counter) does lane-parallel col-LSE
// from gmat + merges 14 rowsums -> global-last batch-finisher emits scalar.
// ---------------------------------------------------------------------------
__global__ __launch_bounds__(NT) void kA_mono(
    const float* __restrict__ text, const float* __restrict__ ipe,
    const int* __restrict__ bbox, const int* __restrict__ attn,
    float* __restrict__ gmat, float* __restrict__ rowsum,
    float* __restrict__ batchtot, int* __restrict__ batch_done,
    int* __restrict__ done_ctr, float* __restrict__ out)
{
  __shared__ __align__(16) float tpl[SCH][NC];
  __shared__ int cnt_s[NP];
  __shared__ int slot_s[NP];
  __shared__ int dlist_s[MAXM];
  __shared__ short vl_s[NL];
  __shared__ short vslot_s[NL];
  __shared__ int wcnt_s[NWV];
  __shared__ float wsum[NWV];
  __shared__ float cacc_s[NWV];
  __shared__ int nv_s, lastA_s, lastB_s;

  const int b = blockIdx.x, rt = blockIdx.y, tid = threadIdx.x;
  const int wv = tid >> 6, lane = tid & 63;

  // ---- phase 1: labels for tokens tid and tid+NT ----
  int lab0, lab1 = -1;
  {
    int4 bb = ((const int4*)bbox)[b * NL + tid];
    int x0 = bb.x / 72, y0 = bb.y / 72, x1 = bb.z / 72, y1 = bb.w / 72;
    lab0 = (x0 == x1 && y0 == y1) ? (y0 * 14 + x0) : -1;
    if (attn[b * NL + tid] == 0) lab0 = -1;
  }
  if (tid < NL - NT) {
    int4 bb = ((const int4*)bbox)[b * NL + NT + tid];
    int x0 = bb.x / 72, y0 = bb.y / 72, x1 = bb.z / 72, y1 = bb.w / 72;
    lab1 = (x0 == x1 && y0 == y1) ? (y0 * 14 + x0) : -1;
    if (attn[b * NL + NT + tid] == 0) lab1 = -1;
  }
  if (tid < NP) { cnt_s[tid] = 0; slot_s[tid] = -1; }
  if (tid == 0) nv_s = 0;
  __syncthreads();
  if (lab0 >= 0) atomicAdd(&cnt_s[lab0], 1);
  if (lab1 >= 0) atomicAdd(&cnt_s[lab1], 1);
  __syncthreads();

  // deterministic slot compaction (identical across a batch's 14 blocks)
  {
    int flagv = (tid < NP && cnt_s[tid] > 0) ? 1 : 0;
    unsigned long long bal = __ballot(flagv);
    int pos = __popcll(bal & ((1ull << lane) - 1ull));
    if (lane == 0) wcnt_s[wv] = __popcll(bal);
    __syncthreads();
    if (flagv) {
      int off = 0;
      for (int w = 0; w < wv; ++w) off += wcnt_s[w];
      int s = off + pos;
      if (s < MAXM) { slot_s[tid] = s; dlist_s[s] = tid; }
    }
  }
  __syncthreads();
  int m = 0;
#pragma unroll
  for (int w = 0; w < NWV; ++w) m += wcnt_s[w];
  m = min(m, MAXM);

  // valid-token list (atomic order only affects block-local rounding)
  if (lab0 >= 0 && slot_s[lab0] >= 0) {
    int t = atomicAdd(&nv_s, 1);
    vl_s[t] = (short)tid; vslot_s[t] = (short)slot_s[lab0];
  }
  if (lab1 >= 0 && slot_s[lab1] >= 0) {
    int t = atomicAdd(&nv_s, 1);
    vl_s[t] = (short)(NT + tid); vslot_s[t] = (short)slot_s[lab1];
  }
  __syncthreads();
  const int nv = nv_s;

  // ---- phases 2+3: per-chunk tpe build in LDS, then row dots + online LSE --
  float rowM[RPW], rowSum[RPW], rowDiag[RPW];
#pragma unroll
  for (int r = 0; r < RPW; ++r) {
    rowM[r] = 0.0f; rowSum[r] = (float)(NP - m); rowDiag[r] = 0.0f;
  }

  const int p0 = rt * RPB + wv * RPW;

  for (int s0 = 0; s0 < m; s0 += SCH) {   // zero iterations when m == 0
    const int sc = min(SCH, m - s0);
    __syncthreads();   // (multi-chunk only) previous chunk's readers done
    for (int i = tid; i < SCH * (NC / 4); i += NT) {
      float4 z = {0.0f, 0.0f, 0.0f, 0.0f};
      ((float4*)tpl)[i] = z;
    }
    __syncthreads();
    // threads own columns c = tid, tid+NT: RMW chains thread-local
    for (int t = 0; t < nv; ++t) {
      int s = (int)vslot_s[t] - s0;
      if (s >= 0 && s < sc) {
        const float* tr = text + ((size_t)b * NL + vl_s[t]) * NC;
        for (int c = tid; c < NC; c += NT) tpl[s][c] += tr[c];
      }
    }
    for (int s = 0; s < sc; ++s) {
      float inv = 1.0f / (float)max(cnt_s[dlist_s[s0 + s]], 1);
      for (int c = tid; c < NC; c += NT) tpl[s][c] *= inv;
    }
    __syncthreads();

    int dls[SCH];
#pragma unroll
    for (int s = 0; s < SCH; ++s)
      dls[s] = (s0 + s < m) ? dlist_s[s0 + s] : -2;

#pragma unroll
    for (int r = 0; r < RPW; ++r) {
      const int p = p0 + r;
      const float* ir = ipe + ((size_t)b * NP + p) * NC;
      float acc[SCH];
#pragma unroll
      for (int s = 0; s < SCH; ++s) acc[s] = 0.0f;
#pragma unroll
      for (int k = 0; k < 3; ++k) {
        const int c = k * 256 + lane * 4;
        float4 x = *(const float4*)(ir + c);
#pragma unroll
        for (int s = 0; s < SCH; ++s) {   // unguarded: tpl zero-filled
          float4 t = *(const float4*)(&tpl[s][c]);
          acc[s] += x.x * t.x + x.y * t.y + x.z * t.z + x.w * t.w;
        }
      }
#pragma unroll
      for (int s = 0; s < SCH; ++s) {
        float v = acc[s];
        for (int off = 32; off > 0; off >>= 1) v += __shfl_xor(v, off, 64);
        acc[s] = v;   // all lanes hold the total
      }
      if (lane == 0) {
#pragma unroll
        for (int s = 0; s < SCH; ++s)
          if (s < sc)   // atomicExch: write-through, device-visible, no fence
            atomicExch(&gmat[((size_t)b * MAXM + s0 + s) * NP + p], acc[s]);
      }
      float cmax = rowM[r];
#pragma unroll
      for (int s = 0; s < SCH; ++s) if (s < sc) cmax = fmaxf(cmax, acc[s]);
      float sum = rowSum[r] * expf(rowM[r] - cmax);
#pragma unroll
      for (int s = 0; s < SCH; ++s) if (s < sc) sum += expf(acc[s] - cmax);
      rowM[r] = cmax; rowSum[r] = sum;
#pragma unroll
      for (int s = 0; s < SCH; ++s) if (dls[s] == p) rowDiag[r] = acc[s];
    }
  }

  // ---- per-wave row partial (m==0 falls through: rm=0, rs=NP -> log(NP)) --
  float wacc = 0.0f;   // identical across lanes of the wave
#pragma unroll
  for (int r = 0; r < RPW; ++r)
    wacc += rowM[r] + logf(rowSum[r]) - rowDiag[r];
  if (lane == 0) wsum[wv] = wacc;
  __syncthreads();     // also drains the gmat atomics (vmcnt(0) before barrier)
  if (tid == 0) {
    float s = 0.0f;
#pragma unroll
    for (int w = 0; w < NWV; ++w) s += wsum[w];
    atomicExch(&rowsum[b * RT + rt], s);
    asm volatile("s_waitcnt vmcnt(0)" ::: "memory");  // rowsum landed
    int prev = atomicAdd(&batch_done[b], 1);
    lastA_s = (prev == RT - 1) ? 1 : 0;
  }
  __syncthreads();
  if (!lastA_s) return;

  // ---- batch-last block: col-LSE over m slots (lane-parallel, RMW reads) --
  float acc = 0.0f;
  for (int s = wv; s < m; s += NWV) {
    float* gc = gmat + ((size_t)b * MAXM + s) * NP;
    float g0 = atomicAdd(&gc[lane], 0.0f);
    float g1 = atomicAdd(&gc[lane + 64], 0.0f);
    float g2 = atomicAdd(&gc[lane + 128], 0.0f);
    float g3 = (lane < NP - 192) ? atomicAdd(&gc[lane + 192], 0.0f) : -1e30f;
    float mx = fmaxf(fmaxf(g0, g1), fmaxf(g2, g3));
    for (int off = 32; off > 0; off >>= 1) mx = fmaxf(mx, __shfl_xor(mx, off, 64));
    float se = expf(g0 - mx) + expf(g1 - mx) + expf(g2 - mx) +
               ((lane < NP - 192) ? expf(g3 - mx) : 0.0f);
    for (int off = 32; off > 0; off >>= 1) se += __shfl_xor(se, off, 64);
    if (lane == 0) acc += (mx + logf(se)) - atomicAdd(&gc[dlist_s[s]], 0.0f);
  }
  // last wave additionally merges the batch's 14 rowsums (slots s==6 mod 7
  // are rare, so this wave is usually free)
  if (wv == NWV - 1) {
    float v = (lane < RT) ? atomicAdd(&rowsum[b * RT + lane], 0.0f) : 0.0f;
    for (int off = 32; off > 0; off >>= 1) v += __shfl_xor(v, off, 64);
    acc += v;   // lane-uniform after butterfly
  }
  if (lane == 0) cacc_s[wv] = acc;
  __syncthreads();
  if (tid == 0) {
    float tot = (float)(NP - m) * logf((float)NP);
#pragma unroll
    for (int w = 0; w < NWV; ++w) tot += cacc_s[w];
    atomicExch(&batchtot[b], tot);
    asm volatile("s_waitcnt vmcnt(0)" ::: "memory");  // batchtot landed
    int prev = atomicAdd(done_ctr, 1);
    lastB_s = (prev == NB - 1) ? 1 : 0;
  }
  __syncthreads();
  if (lastB_s && tid < 64) {
    float v = atomicAdd(&batchtot[tid], 0.0f);   // RMW read, coherent
    for (int off = 32; off > 0; off >>= 1) v += __shfl_xor(v, off, 64);
    if (tid == 0) out[0] = v / (float)(2 * NB * NP);
  }
}

extern "C" void kernel_launch(void* const* d_in, const int* in_sizes, int n_in,
                              void* d_out, int out_size, void* d_ws, size_t ws_size,
                              hipStream_t stream) {
  const float* text = (const float*)d_in[0];
  const float* ipe  = (const float*)d_in[1];
  const int*   bbox = (const int*)d_in[2];
  const int*   attn = (const int*)d_in[3];

  float* gmat       = (float*)d_ws;                      // NB*MAXM*NP floats
  float* rowsum     = gmat + (size_t)NB * MAXM * NP;     // NB*RT floats
  float* batchtot   = rowsum + (size_t)NB * RT;          // NB floats
  int*   batch_done = (int*)(batchtot + NB);             // NB ints
  int*   done_c     = batch_done + NB;                   // 1 int

  hipMemsetAsync(batch_done, 0, (NB + 1) * sizeof(int), stream);

  dim3 g(NB, RT);
  kA_mono<<<g, NT, 0, stream>>>(text, ipe, bbox, attn, gmat, rowsum,
                                batchtot, batch_done, done_c, (float*)d_out);
}

// Round 11
// 26.823 us; speedup vs baseline: 1.2047x; 1.2047x over previous
//
#include <hip/hip_runtime.h>
#include <math.h>

#define NB 64
#define NL 512
#define NC 768
#define NP 196
#define MAXM 32      // max distinct valid labels per batch (m ~ Poisson(1.31))
#define RT 14        // kernel-A blocks per batch
#define RPB 14       // rows per block (RT*RPB == NP)
#define RPW 2        // rows per wave (7 waves * RPW == RPB)
#define NWV 7        // waves per block
#define NT 448       // threads per block
#define SCH 4        // tpe slots per LDS chunk

// ---------------------------------------------------------------------------
// Kernel A (R9 + entry ipe register prefetch): fused labels + tpe-in-LDS +
// ipe row streaming. Grid (NB, RT), 448 threads. The wave's 2 ipe rows (24
// floats/lane) are loaded into registers right after the any-valid check, so
// the 28 MB HBM stream overlaps the label/compaction/tpe prologue. Plain
// stores only (gmat, rowsum); no fences, no global atomics.
// ---------------------------------------------------------------------------
__global__ __launch_bounds__(NT) void kA_fused(
    const float* __restrict__ text, const float* __restrict__ ipe,
    const int* __restrict__ bbox, const int* __restrict__ attn,
    float* __restrict__ gmat, float* __restrict__ rowsum,
    int* __restrict__ m_g, int* __restrict__ dlist_g, int* __restrict__ done_ctr)
{
  __shared__ __align__(16) float tpl[SCH][NC];
  __shared__ int cnt_s[NP];
  __shared__ int slot_s[NP];
  __shared__ int dlist_s[MAXM];
  __shared__ short vl_s[NL];
  __shared__ short vslot_s[NL];
  __shared__ int wcnt_s[NWV];
  __shared__ float wsum[NWV];
  __shared__ int nv_s, any_s;

  const int b = blockIdx.x, rt = blockIdx.y, tid = threadIdx.x;
  const int wv = tid >> 6, lane = tid & 63;
  const int p0 = rt * RPB + wv * RPW;
  const int widx = b * RT + rt;

  if (b == 0 && rt == 0 && tid == 0) *done_ctr = 0;  // consumed by kB only

  // ---- phase 0: init LDS, then labels for tokens tid and tid+NT ----
  if (tid < NP) { cnt_s[tid] = 0; slot_s[tid] = -1; }
  if (tid == 0) { nv_s = 0; any_s = 0; }
  __syncthreads();

  int lab0, lab1 = -1;
  {
    int4 bb = ((const int4*)bbox)[b * NL + tid];
    int x0 = bb.x / 72, y0 = bb.y / 72, x1 = bb.z / 72, y1 = bb.w / 72;
    lab0 = (x0 == x1 && y0 == y1) ? (y0 * 14 + x0) : -1;
    if (attn[b * NL + tid] == 0) lab0 = -1;
  }
  if (tid < NL - NT) {
    int4 bb = ((const int4*)bbox)[b * NL + NT + tid];
    int x0 = bb.x / 72, y0 = bb.y / 72, x1 = bb.z / 72, y1 = bb.w / 72;
    lab1 = (x0 == x1 && y0 == y1) ? (y0 * 14 + x0) : -1;
    if (attn[b * NL + NT + tid] == 0) lab1 = -1;
  }
  if (lab0 >= 0) { any_s = 1; atomicAdd(&cnt_s[lab0], 1); }
  if (lab1 >= 0) { any_s = 1; atomicAdd(&cnt_s[lab1], 1); }
  __syncthreads();

  // ---- m == 0 fast path: analytic row terms, skip the ipe stream ----
  if (!any_s) {
    if (tid == 0) {
      rowsum[widx] = (float)RPB * logf((float)NP);
      if (rt == 0) m_g[b] = 0;
    }
    return;
  }

  // ---- issue ipe register prefetch NOW: overlaps the rest of the prologue --
  float4 xr[RPW][3];
  {
    const float* ir = ipe + ((size_t)b * NP + p0) * NC + lane * 4;
#pragma unroll
    for (int r = 0; r < RPW; ++r)
#pragma unroll
      for (int k = 0; k < 3; ++k)
        xr[r][k] = *(const float4*)(ir + r * NC + k * 256);
  }

  // ---- deterministic slot compaction (identical across a batch's blocks) --
  {
    int flagv = (tid < NP && cnt_s[tid] > 0) ? 1 : 0;
    unsigned long long bal = __ballot(flagv);
    int pos = __popcll(bal & ((1ull << lane) - 1ull));
    if (lane == 0) wcnt_s[wv] = __popcll(bal);
    __syncthreads();
    if (flagv) {
      int off = 0;
      for (int w = 0; w < wv; ++w) off += wcnt_s[w];
      int s = off + pos;
      if (s < MAXM) { slot_s[tid] = s; dlist_s[s] = tid; }
    }
  }
  __syncthreads();
  int m = 0;
#pragma unroll
  for (int w = 0; w < NWV; ++w) m += wcnt_s[w];
  m = min(m, MAXM);

  // valid-token list (atomic order only affects block-local rounding)
  if (lab0 >= 0 && slot_s[lab0] >= 0) {
    int t = atomicAdd(&nv_s, 1);
    vl_s[t] = (short)tid; vslot_s[t] = (short)slot_s[lab0];
  }
  if (lab1 >= 0 && slot_s[lab1] >= 0) {
    int t = atomicAdd(&nv_s, 1);
    vl_s[t] = (short)(NT + tid); vslot_s[t] = (short)slot_s[lab1];
  }
  __syncthreads();
  const int nv = nv_s;

  // metadata for kernel B (rt==0 block only; values identical across rt)
  if (rt == 0) {
    if (tid == 0) m_g[b] = m;
    if (tid < m) dlist_g[b * MAXM + tid] = dlist_s[tid];
  }

  // ---- per-chunk tpe build in LDS, then row dots + online LSE ----
  float rowM[RPW], rowSum[RPW], rowDiag[RPW];
#pragma unroll
  for (int r = 0; r < RPW; ++r) {
    rowM[r] = 0.0f; rowSum[r] = (float)(NP - m); rowDiag[r] = 0.0f;
  }

  for (int s0 = 0; s0 < m; s0 += SCH) {
    const int sc = min(SCH, m - s0);
    __syncthreads();   // (multi-chunk only) previous chunk's readers done
    for (int i = tid; i < SCH * (NC / 4); i += NT) {
      float4 z = {0.0f, 0.0f, 0.0f, 0.0f};
      ((float4*)tpl)[i] = z;
    }
    __syncthreads();
    // threads own columns c = tid, tid+NT: RMW chains thread-local
    for (int t = 0; t < nv; ++t) {
      int s = (int)vslot_s[t] - s0;
      if (s >= 0 && s < sc) {
        const float* tr = text + ((size_t)b * NL + vl_s[t]) * NC;
        for (int c = tid; c < NC; c += NT) tpl[s][c] += tr[c];
      }
    }
    for (int s = 0; s < sc; ++s) {
      float inv = 1.0f / (float)max(cnt_s[dlist_s[s0 + s]], 1);
      for (int c = tid; c < NC; c += NT) tpl[s][c] *= inv;
    }
    __syncthreads();

    int dls[SCH];
#pragma unroll
    for (int s = 0; s < SCH; ++s)
      dls[s] = (s0 + s < m) ? dlist_s[s0 + s] : -2;

#pragma unroll
    for (int r = 0; r < RPW; ++r) {
      const int p = p0 + r;
      float acc[SCH];
#pragma unroll
      for (int s = 0; s < SCH; ++s) acc[s] = 0.0f;
#pragma unroll
      for (int k = 0; k < 3; ++k) {
        const int c = k * 256 + lane * 4;
        float4 x = xr[r][k];                     // register-prefetched ipe
#pragma unroll
        for (int s = 0; s < SCH; ++s) {          // unguarded: tpl zero-filled
          float4 t = *(const float4*)(&tpl[s][c]);
          acc[s] += x.x * t.x + x.y * t.y + x.z * t.z + x.w * t.w;
        }
      }
#pragma unroll
      for (int s = 0; s < SCH; ++s) {
        float v = acc[s];
        for (int off = 32; off > 0; off >>= 1) v += __shfl_xor(v, off, 64);
        acc[s] = v;   // all lanes hold the total
      }
      if (lane == 0) {
#pragma unroll
        for (int s = 0; s < SCH; ++s)
          if (s < sc) gmat[((size_t)b * MAXM + s0 + s) * NP + p] = acc[s];
      }
      float cmax = rowM[r];
#pragma unroll
      for (int s = 0; s < SCH; ++s) if (s < sc) cmax = fmaxf(cmax, acc[s]);
      float sum = rowSum[r] * expf(rowM[r] - cmax);
#pragma unroll
      for (int s = 0; s < SCH; ++s) if (s < sc) sum += expf(acc[s] - cmax);
      rowM[r] = cmax; rowSum[r] = sum;
#pragma unroll
      for (int s = 0; s < SCH; ++s) if (dls[s] == p) rowDiag[r] = acc[s];
    }
  }

  float wacc = 0.0f;   // identical across lanes of the wave
#pragma unroll
  for (int r = 0; r < RPW; ++r)
    wacc += rowM[r] + logf(rowSum[r]) - rowDiag[r];
  if (lane == 0) wsum[wv] = wacc;
  __syncthreads();
  if (tid == 0) {
    float s = 0.0f;
#pragma unroll
    for (int w = 0; w < NWV; ++w) s += wsum[w];
    rowsum[widx] = s;   // plain store; kB reads after kernel boundary
  }
}

// ---------------------------------------------------------------------------
// Kernel B (R9 proven, verbatim): per batch, sum the 14 rowsums + column LSE
// over the m valid columns + (P-m)*log(P); last-finishing block reduces to
// the final scalar. 64 blocks, 256 threads.
// ---------------------------------------------------------------------------
__global__ __launch_bounds__(256) void kB_cols(
    const int* __restrict__ m_g, const int* __restrict__ dlist_g,
    const float* __restrict__ gmat, const float* __restrict__ rowsum,
    float* __restrict__ partial, int* __restrict__ done_ctr,
    float* __restrict__ out)
{
  const int b = blockIdx.x, tid = threadIdx.x, wv = tid >> 6, lane = tid & 63;
  __shared__ float wacc_s[4];
  __shared__ float rsum_s;
  __shared__ int last_s;
  const int m = m_g[b];

  if (tid == 0) {
    float t = 0.0f;
#pragma unroll
    for (int i = 0; i < RT; ++i) t += rowsum[b * RT + i];
    rsum_s = t;
  }

  float acc = 0.0f;
  for (int s = wv; s < m; s += 4) {
    const float* gc = gmat + ((size_t)b * MAXM + s) * NP;
    float g0 = gc[lane];
    float g1 = gc[lane + 64];
    float g2 = gc[lane + 128];
    float g3 = (lane < NP - 192) ? gc[lane + 192] : -1e30f;
    float mx = fmaxf(fmaxf(g0, g1), fmaxf(g2, g3));
    for (int off = 32; off > 0; off >>= 1) mx = fmaxf(mx, __shfl_xor(mx, off, 64));
    float se = expf(g0 - mx) + expf(g1 - mx) + expf(g2 - mx) +
               ((lane < NP - 192) ? expf(g3 - mx) : 0.0f);
    for (int off = 32; off > 0; off >>= 1) se += __shfl_xor(se, off, 64);
    if (lane == 0) acc += (mx + logf(se)) - gc[dlist_g[b * MAXM + s]];
  }
  if (lane == 0) wacc_s[wv] = acc;
  __syncthreads();
  if (tid == 0) {
    float tot = rsum_s + wacc_s[0] + wacc_s[1] + wacc_s[2] + wacc_s[3] +
                (float)(NP - m) * logf((float)NP);
    atomicExch(&partial[b], tot);          // coherent write, no zeroing needed
    __threadfence();                       // release partial before counter
    int prev = atomicAdd(done_ctr, 1);
    last_s = (prev == NB - 1) ? 1 : 0;
  }
  __syncthreads();
  if (last_s) {
    __threadfence();                       // acquire side
    if (tid < 64) {
      // atomic RMW read: coherent across XCD L2s
      float v = atomicAdd(&partial[tid], 0.0f);
      for (int off = 32; off > 0; off >>= 1) v += __shfl_xor(v, off, 64);
      if (tid == 0) out[0] = v / (float)(2 * NB * NP);
    }
  }
}

extern "C" void kernel_launch(void* const* d_in, const int* in_sizes, int n_in,
                              void* d_out, int out_size, void* d_ws, size_t ws_size,
                              hipStream_t stream) {
  const float* text = (const float*)d_in[0];
  const float* ipe  = (const float*)d_in[1];
  const int*   bbox = (const int*)d_in[2];
  const int*   attn = (const int*)d_in[3];

  float* gmat    = (float*)d_ws;                       // NB*MAXM*NP floats
  float* rowsum  = gmat + (size_t)NB * MAXM * NP;      // NB*RT floats
  float* partial = rowsum + (size_t)NB * RT;           // NB floats
  int*   m_g     = (int*)(partial + NB);               // NB ints
  int*   dlist_g = m_g + NB;                           // NB*MAXM ints
  int*   done_c  = dlist_g + NB * MAXM;                // 1 int

  dim3 gA(NB, RT);
  kA_fused<<<gA, NT, 0, stream>>>(text, ipe, bbox, attn, gmat, rowsum,
                                  m_g, dlist_g, done_c);
  kB_cols<<<NB, 256, 0, stream>>>(m_g, dlist_g, gmat, rowsum, partial,
                                  done_c, (float*)d_out);
}